// Round 1
// baseline (181.020 us; speedup 1.0000x reference)
//
#include <hip/hip_runtime.h>

#define BB 4
#define TT 2048
#define DD 1024
#define SCALE 32.0f
#define NTILE 136   // lower-triangular 128x128 tiles per batch: 16*17/2

typedef _Float16 f16;
typedef __attribute__((ext_vector_type(4))) _Float16 half4v;
typedef __attribute__((ext_vector_type(8))) _Float16 half8v;
typedef __attribute__((ext_vector_type(16))) float f32x16;

static __device__ inline half8v ld_frag(const f16* p) {
    half4v a = *(const half4v*)p;
    half4v b = *(const half4v*)(p + 4);
    half8v r;
    r[0] = a[0]; r[1] = a[1]; r[2] = a[2]; r[3] = a[3];
    r[4] = b[0]; r[5] = b[1]; r[6] = b[2]; r[7] = b[3];
    return r;
}

// ---------------------------------------------------------------------------
// K1: S = (32*Q) * K^T, fp16 hi/lo x3 MFMA passes, lower-triangular tiles only
// ---------------------------------------------------------------------------
__global__ __launch_bounds__(256, 2) void k1_qk(const float* __restrict__ Q,
                                                const float* __restrict__ Kmat,
                                                float* __restrict__ S) {
    __shared__ f16 Ah[128][36], Al[128][36], Bh[128][36], Bl[128][36];

    int bid = blockIdx.x;
    int b = bid / NTILE, r = bid % NTILE;
    int mi = 0;
    while ((mi + 1) * (mi + 2) / 2 <= r) ++mi;
    int nj = r - mi * (mi + 1) / 2;

    const float* Qb = Q + ((size_t)b * TT + (size_t)mi * 128) * DD;
    const float* Kb = Kmat + ((size_t)b * TT + (size_t)nj * 128) * DD;
    float* Sb = S + (size_t)b * TT * TT + (size_t)(mi * 128) * TT + nj * 128;

    int tid = threadIdx.x;
    int lane = tid & 63;
    int wave = tid >> 6;
    int l31 = lane & 31, lhi = lane >> 5;
    int wrow = wave >> 1, wcol = wave & 1;

    int r0 = tid >> 1;            // staging row 0..127
    int c0 = (tid & 1) * 16;      // staging col half

    f32x16 acc[2][2] = {};

    float4 abuf[4], bbuf[4];
#pragma unroll
    for (int j = 0; j < 4; ++j) {
        abuf[j] = *(const float4*)(Qb + (size_t)r0 * DD + c0 + 4 * j);
        bbuf[j] = *(const float4*)(Kb + (size_t)r0 * DD + c0 + 4 * j);
    }

    for (int ch = 0; ch < DD / 32; ++ch) {
        __syncthreads();   // previous compute done; LDS reusable
#pragma unroll
        for (int j = 0; j < 4; ++j) {
            float4 a = abuf[j], bq = bbuf[j];
            float ax[4] = {a.x * SCALE, a.y * SCALE, a.z * SCALE, a.w * SCALE};
            float bx[4] = {bq.x, bq.y, bq.z, bq.w};
            half4v ahv, alv, bhv, blv;
#pragma unroll
            for (int e = 0; e < 4; ++e) {
                f16 h = (f16)ax[e];
                ahv[e] = h;
                alv[e] = (f16)(ax[e] - (float)h);
                f16 g = (f16)bx[e];
                bhv[e] = g;
                blv[e] = (f16)(bx[e] - (float)g);
            }
            *(half4v*)&Ah[r0][c0 + 4 * j] = ahv;
            *(half4v*)&Al[r0][c0 + 4 * j] = alv;
            *(half4v*)&Bh[r0][c0 + 4 * j] = bhv;
            *(half4v*)&Bl[r0][c0 + 4 * j] = blv;
        }
        __syncthreads();
        if (ch + 1 < DD / 32) {    // prefetch next chunk (overlaps compute)
            int ck = (ch + 1) * 32;
#pragma unroll
            for (int j = 0; j < 4; ++j) {
                abuf[j] = *(const float4*)(Qb + (size_t)r0 * DD + ck + c0 + 4 * j);
                bbuf[j] = *(const float4*)(Kb + (size_t)r0 * DD + ck + c0 + 4 * j);
            }
        }
#pragma unroll
        for (int ks = 0; ks < 2; ++ks) {
            int kb = ks * 16 + lhi * 8;
            half8v ahf[2], alf[2], bhf[2], blf[2];
#pragma unroll
            for (int f = 0; f < 2; ++f) {
                ahf[f] = ld_frag(&Ah[wrow * 64 + f * 32 + l31][kb]);
                alf[f] = ld_frag(&Al[wrow * 64 + f * 32 + l31][kb]);
                bhf[f] = ld_frag(&Bh[wcol * 64 + f * 32 + l31][kb]);
                blf[f] = ld_frag(&Bl[wcol * 64 + f * 32 + l31][kb]);
            }
#pragma unroll
            for (int fm = 0; fm < 2; ++fm)
#pragma unroll
                for (int fn = 0; fn < 2; ++fn) {
                    acc[fm][fn] = __builtin_amdgcn_mfma_f32_32x32x16_f16(ahf[fm], bhf[fn], acc[fm][fn], 0, 0, 0);
                    acc[fm][fn] = __builtin_amdgcn_mfma_f32_32x32x16_f16(ahf[fm], blf[fn], acc[fm][fn], 0, 0, 0);
                    acc[fm][fn] = __builtin_amdgcn_mfma_f32_32x32x16_f16(alf[fm], bhf[fn], acc[fm][fn], 0, 0, 0);
                }
        }
    }
    // epilogue: C layout (32x32): col = lane&31, row = (g&3)+8*(g>>2)+4*(lane>>5)
#pragma unroll
    for (int fm = 0; fm < 2; ++fm)
#pragma unroll
        for (int fn = 0; fn < 2; ++fn)
#pragma unroll
            for (int g = 0; g < 16; ++g) {
                int rr = (g & 3) + 8 * (g >> 2) + 4 * lhi;
                int row = wrow * 64 + fm * 32 + rr;
                int col = wcol * 64 + fn * 32 + l31;
                Sb[(size_t)row * TT + col] = acc[fm][fn][g];
            }
}

// ---------------------------------------------------------------------------
// K1b: per-row softmax S(f32) -> P(fp16, normalized, zero-padded to tile end)
// ---------------------------------------------------------------------------
__global__ __launch_bounds__(256) void k1b_softmax(const float* __restrict__ S,
                                                   f16* __restrict__ P) {
    __shared__ float red[4];
    int rowid = blockIdx.x;
    int b = rowid >> 11, t = rowid & (TT - 1);
    const float* Sr = S + (size_t)b * TT * TT + (size_t)t * TT;
    f16* Pr = P + (size_t)b * TT * TT + (size_t)t * TT;
    int tid = threadIdx.x;
    int nv = t + 1;
    int rowend = ((t >> 7) + 1) << 7;

    float m = -3.0e38f;
    for (int c = tid; c < nv; c += 256) m = fmaxf(m, Sr[c]);
#pragma unroll
    for (int o = 32; o > 0; o >>= 1) m = fmaxf(m, __shfl_xor(m, o));
    if ((tid & 63) == 0) red[tid >> 6] = m;
    __syncthreads();
    m = fmaxf(fmaxf(red[0], red[1]), fmaxf(red[2], red[3]));
    __syncthreads();

    float s = 0.f;
    for (int c = tid; c < nv; c += 256) s += exp2f((Sr[c] - m) * 1.4426950408889634f);
#pragma unroll
    for (int o = 32; o > 0; o >>= 1) s += __shfl_xor(s, o);
    if ((tid & 63) == 0) red[tid >> 6] = s;
    __syncthreads();
    s = red[0] + red[1] + red[2] + red[3];
    float inv = 1.0f / s;

    for (int c = tid; c < rowend; c += 256) {
        float p = (c < nv) ? exp2f((Sr[c] - m) * 1.4426950408889634f) * inv : 0.0f;
        Pr[c] = (f16)p;
    }
}

// ---------------------------------------------------------------------------
// K2: O = P * V (fp16 MFMA), causal-trimmed K range, V transposed in LDS
// ---------------------------------------------------------------------------
__global__ __launch_bounds__(256, 2) void k2_pv(const f16* __restrict__ P,
                                                const float* __restrict__ V,
                                                float* __restrict__ O) {
    __shared__ f16 Pa[128][36];
    __shared__ f16 Vt[128][36];

    int bid = blockIdx.x;
    int b = bid >> 7;
    int rest = bid & 127;
    int mi = rest >> 3, nj = rest & 7;
    int kend = (mi + 1) * 128;

    const f16* Pb = P + (size_t)b * TT * TT + (size_t)(mi * 128) * TT;
    const float* Vb = V + (size_t)b * TT * DD + nj * 128;
    float* Ob = O + (size_t)b * TT * DD + (size_t)(mi * 128) * DD + nj * 128;

    int tid = threadIdx.x;
    int lane = tid & 63;
    int wave = tid >> 6;
    int l31 = lane & 31, lhi = lane >> 5;
    int wrow = wave >> 1, wcol = wave & 1;

    f32x16 acc[2][2] = {};

    int pr = tid >> 1, pc = (tid & 1) * 16;   // P staging map
    int vk = tid >> 3, vn = (tid & 7) * 16;   // V staging map

    uint2 pbuf[4];
    float4 vbuf[4];
#pragma unroll
    for (int j = 0; j < 4; ++j) {
        pbuf[j] = *(const uint2*)(Pb + (size_t)pr * TT + pc + 4 * j);
        vbuf[j] = *(const float4*)(Vb + (size_t)vk * DD + vn + 4 * j);
    }

    for (int ck = 0; ck < kend; ck += 32) {
        __syncthreads();
#pragma unroll
        for (int j = 0; j < 4; ++j) {
            *(uint2*)&Pa[pr][pc + 4 * j] = pbuf[j];
            float4 v = vbuf[j];
            float vv[4] = {v.x, v.y, v.z, v.w};
            int n0 = vn + 4 * j;
#pragma unroll
            for (int e = 0; e < 4; ++e) {
                int n = n0 + e;
                Vt[n][vk ^ ((((unsigned)n >> 4) & 3) << 3)] = (f16)vv[e];
            }
        }
        __syncthreads();
        if (ck + 32 < kend) {
            int cn = ck + 32;
#pragma unroll
            for (int j = 0; j < 4; ++j) {
                pbuf[j] = *(const uint2*)(Pb + (size_t)pr * TT + cn + pc + 4 * j);
                vbuf[j] = *(const float4*)(Vb + (size_t)(cn + vk) * DD + vn + 4 * j);
            }
        }
#pragma unroll
        for (int ks = 0; ks < 2; ++ks) {
            int kb = ks * 16 + lhi * 8;
            half8v paf[2], vbf[2];
#pragma unroll
            for (int f = 0; f < 2; ++f) {
                paf[f] = ld_frag(&Pa[wrow * 64 + f * 32 + l31][kb]);
                int n = wcol * 64 + f * 32 + l31;
                int kbs = kb ^ ((((unsigned)n >> 4) & 3) << 3);
                vbf[f] = ld_frag(&Vt[n][kbs]);
            }
#pragma unroll
            for (int fm = 0; fm < 2; ++fm)
#pragma unroll
                for (int fn = 0; fn < 2; ++fn)
                    acc[fm][fn] = __builtin_amdgcn_mfma_f32_32x32x16_f16(paf[fm], vbf[fn], acc[fm][fn], 0, 0, 0);
        }
    }
#pragma unroll
    for (int fm = 0; fm < 2; ++fm)
#pragma unroll
        for (int fn = 0; fn < 2; ++fn)
#pragma unroll
            for (int g = 0; g < 16; ++g) {
                int rr = (g & 3) + 8 * (g >> 2) + 4 * lhi;
                int row = wrow * 64 + fm * 32 + rr;
                int col = wcol * 64 + fn * 32 + l31;
                Ob[(size_t)row * DD + col] = acc[fm][fn][g];
            }
}

// ---------------------------------------------------------------------------
// Fallback (ws too small): per-row fp32 online-softmax attention. Slow, correct.
// ---------------------------------------------------------------------------
__global__ __launch_bounds__(256) void fa_fallback(const float* __restrict__ Q,
                                                   const float* __restrict__ Kmat,
                                                   const float* __restrict__ V,
                                                   float* __restrict__ O) {
    __shared__ float qs[DD];
    __shared__ float osum[DD];
    __shared__ float red[4];
    int rowid = blockIdx.x;
    int b = rowid >> 11, t = rowid & (TT - 1);
    const float* q = Q + ((size_t)b * TT + t) * DD;
    int tid = threadIdx.x;
    for (int j = tid; j < DD; j += 256) { qs[j] = q[j] * SCALE; osum[j] = 0.f; }
    __syncthreads();
    float m = -3.0e38f, l = 0.f;
    for (int s = 0; s <= t; ++s) {
        const float* kr = Kmat + ((size_t)b * TT + s) * DD;
        float part = 0.f;
#pragma unroll
        for (int j = 0; j < 4; ++j) part += qs[tid * 4 + j] * kr[tid * 4 + j];
#pragma unroll
        for (int o = 32; o > 0; o >>= 1) part += __shfl_xor(part, o);
        if ((tid & 63) == 0) red[tid >> 6] = part;
        __syncthreads();
        float dot = red[0] + red[1] + red[2] + red[3];
        float mn = fmaxf(m, dot);
        float f = exp2f((m - mn) * 1.44269504f);
        float e = exp2f((dot - mn) * 1.44269504f);
        l = l * f + e;
        const float* vr = V + ((size_t)b * TT + s) * DD;
#pragma unroll
        for (int j = 0; j < 4; ++j) {
            int c = tid * 4 + j;
            osum[c] = osum[c] * f + e * vr[c];
        }
        m = mn;
        __syncthreads();
    }
    float inv = 1.f / l;
    for (int j = tid; j < DD; j += 256) O[((size_t)b * TT + t) * DD + j] = osum[j] * inv;
}

extern "C" void kernel_launch(void* const* d_in, const int* in_sizes, int n_in,
                              void* d_out, int out_size, void* d_ws, size_t ws_size,
                              hipStream_t stream) {
    const float* Q = (const float*)d_in[0];
    const float* K = (const float*)d_in[1];
    const float* V = (const float*)d_in[2];
    float* O = (float*)d_out;

    size_t sbytes = (size_t)BB * TT * TT * 4;   // 64 MiB logits
    size_t pbytes = (size_t)BB * TT * TT * 2;   // 32 MiB fp16 probs

    if (ws_size >= sbytes + pbytes) {
        float* S = (float*)d_ws;
        f16* P = (f16*)((char*)d_ws + sbytes);
        hipLaunchKernelGGL(k1_qk, dim3(BB * NTILE), dim3(256), 0, stream, Q, K, S);
        hipLaunchKernelGGL(k1b_softmax, dim3(BB * TT), dim3(256), 0, stream, S, P);
        hipLaunchKernelGGL(k2_pv, dim3(BB * 16 * 8), dim3(256), 0, stream, P, V, O);
    } else {
        hipLaunchKernelGGL(fa_fallback, dim3(BB * TT), dim3(256), 0, stream, Q, K, V, O);
    }
}

// Round 2
// 153.658 us; speedup vs baseline: 1.1781x; 1.1781x over previous
//
#include <hip/hip_runtime.h>

#define BB 4
#define TT 2048
#define DD 1024
#define SCALE 32.0f
#define NTILE 136   // lower-triangular 128x128 tiles per batch: 16*17/2
#define L2E 1.4426950408889634f

typedef _Float16 f16;
typedef __attribute__((ext_vector_type(4))) _Float16 half4v;
typedef __attribute__((ext_vector_type(8))) _Float16 half8v;
typedef __attribute__((ext_vector_type(16))) float f32x16;

typedef const __attribute__((address_space(1))) unsigned int* gas_u32;
typedef __attribute__((address_space(3))) unsigned int* las_u32;

static __device__ inline void gload16(const void* g, void* l) {
    __builtin_amdgcn_global_load_lds((gas_u32)g, (las_u32)l, 16, 0, 0);
}

static __device__ inline half8v ld_frag(const f16* p) {
    half4v a = *(const half4v*)p;
    half4v b = *(const half4v*)(p + 4);
    half8v r;
    r[0] = a[0]; r[1] = a[1]; r[2] = a[2]; r[3] = a[3];
    r[4] = b[0]; r[5] = b[1]; r[6] = b[2]; r[7] = b[3];
    return r;
}

// ===========================================================================
// NEW PATH (needs 144 MiB ws)
// Tiled-swizzled fp16 layouts, 16 KiB per (tile, k-chunk):
//   granule(r, slot) at byte r*128 + ((slot ^ (r&7))<<4), slot = k0>>3
//   Qt/Kt: [b][tile16][ck32(BK=32)] rows=128 t-rows, slots 0-3 hi, 4-7 lo
//   Vt/Pt: [b][tile][ck32(BK=64)]  rows=128 (n or t-rows), slots 0-7 plain
// ===========================================================================

// --- P0a: repack Q (x32) and K into hi/lo fp16 tiled-swizzled layout -------
__global__ __launch_bounds__(256) void repack_qk(const float* __restrict__ Q,
                                                 const float* __restrict__ K,
                                                 f16* __restrict__ Qt,
                                                 f16* __restrict__ Kt) {
    const int total = 2 * BB * TT * (DD / 8);   // 2,097,152 groups of 8
    for (int gid = blockIdx.x * 256 + threadIdx.x; gid < total; gid += gridDim.x * 256) {
        int g = gid & 127;            // 8-elem group within row (k/8)
        int t = (gid >> 7) & 2047;
        int b = (gid >> 18) & 3;
        int which = gid >> 20;
        const float* src = which ? K : Q;
        f16* dst = which ? Kt : Qt;
        float sc = which ? 1.0f : SCALE;
        const float* p = src + ((size_t)(b * TT + t)) * DD + g * 8;
        float4 x0 = *(const float4*)p;
        float4 x1 = *(const float4*)(p + 4);
        float vv[8] = {x0.x, x0.y, x0.z, x0.w, x1.x, x1.y, x1.z, x1.w};
        half8v hi, lo;
#pragma unroll
        for (int e = 0; e < 8; ++e) {
            float x = vv[e] * sc;
            f16 h = (f16)x;
            hi[e] = h;
            lo[e] = (f16)(x - (float)h);
        }
        int r = t & 127, mi = t >> 7, ck = g >> 2, gq = g & 3;
        char* base = (char*)dst + ((size_t)((b * 16 + mi) * 32 + ck)) * 16384 + r * 128;
        *(half8v*)(base + ((gq ^ (r & 7)) << 4)) = hi;
        *(half8v*)(base + (((4 + gq) ^ (r & 7)) << 4)) = lo;
    }
}

// --- P0b: V -> V^T fp16 tiled-swizzled ------------------------------------
__global__ __launch_bounds__(256) void transpose_v(const float* __restrict__ V,
                                                   f16* __restrict__ Vt) {
    __shared__ float Vs[64][129];
    int bid = blockIdx.x;                 // 4 * 32 * 8 = 1024 blocks
    int b = bid >> 8, kb = (bid >> 3) & 31, nj = bid & 7;
    const float* src = V + ((size_t)(b * TT + kb * 64)) * DD + nj * 128;
    int tid = threadIdx.x;
#pragma unroll
    for (int it = 0; it < 8; ++it) {
        int f4 = it * 256 + tid;
        int row = f4 >> 5, c4 = f4 & 31;
        float4 x = *(const float4*)(src + (size_t)row * DD + c4 * 4);
        Vs[row][c4 * 4 + 0] = x.x;
        Vs[row][c4 * 4 + 1] = x.y;
        Vs[row][c4 * 4 + 2] = x.z;
        Vs[row][c4 * 4 + 3] = x.w;
    }
    __syncthreads();
    char* dbase = (char*)Vt + ((size_t)((b * 8 + nj) * 32 + kb)) * 16384;
#pragma unroll
    for (int it = 0; it < 4; ++it) {
        int gid = it * 256 + tid;
        int n = gid >> 3, s = gid & 7;
        half8v h;
#pragma unroll
        for (int j = 0; j < 8; ++j) h[j] = (f16)Vs[s * 8 + j][n];
        *(half8v*)(dbase + n * 128 + ((s ^ (n & 7)) << 4)) = h;
    }
}

// --- K1: S = (32Q) K^T, fp16 hi/lo 3-pass, gload_lds 2-phase ---------------
__global__ __launch_bounds__(256, 2) void k1_qk2(const f16* __restrict__ Qt,
                                                 const f16* __restrict__ Kt,
                                                 float* __restrict__ S) {
    __shared__ char lds[65536];   // 2 bufs x (A 16K | B 16K)

    int bid0 = blockIdx.x;
    int bid = (bid0 & 7) * (BB * NTILE / 8) + (bid0 >> 3);   // XCD swizzle (544%8==0)
    int b = bid / NTILE, r = bid % NTILE;
    int mi = 0;
    while ((mi + 1) * (mi + 2) / 2 <= r) ++mi;
    int nj = r - mi * (mi + 1) / 2;

    const char* Abase = (const char*)Qt + ((size_t)((b * 16 + mi) * 32)) * 16384;
    const char* Bbase = (const char*)Kt + ((size_t)((b * 16 + nj) * 32)) * 16384;
    float* Sb = S + (size_t)b * TT * TT + (size_t)(mi * 128) * TT + nj * 128;

    int tid = threadIdx.x;
    int lane = tid & 63;
    int wv = tid >> 6;
    int l31 = lane & 31, lhi = lane >> 5;
    int wrow = wv >> 1, wcol = wv & 1;

    // frag byte offsets (hi); lo = hi ^ 64
    int aoff[2][2], boff[2][2];
#pragma unroll
    for (int fm = 0; fm < 2; ++fm) {
        int ra = wrow * 64 + fm * 32 + l31;
        int rb = wcol * 64 + fm * 32 + l31;
#pragma unroll
        for (int ks = 0; ks < 2; ++ks) {
            int slot = ks * 2 + lhi;
            aoff[fm][ks] = ra * 128 + ((slot ^ (ra & 7)) << 4);
            boff[fm][ks] = rb * 128 + ((slot ^ (rb & 7)) << 4);
        }
    }
    int lane_go = (wv * 256 + lane) * 16;     // per-lane global granule byte
    int lane_lo = (wv * 256) * 16;            // wave-uniform LDS base byte

    f32x16 acc[2][2] = {};

#define K1_STAGE(CK, BUF)                                                       \
    {                                                                           \
        const char* ga = Abase + (size_t)(CK) * 16384 + lane_go;                \
        const char* gb = Bbase + (size_t)(CK) * 16384 + lane_go;                \
        char* la = lds + (BUF) * 32768 + lane_lo;                               \
        char* lb = la + 16384;                                                  \
        _Pragma("unroll") for (int i = 0; i < 4; ++i)                           \
            gload16(ga + i * 1024, la + i * 1024);                              \
        _Pragma("unroll") for (int i = 0; i < 4; ++i)                           \
            gload16(gb + i * 1024, lb + i * 1024);                              \
    }

    K1_STAGE(0, 0);
    int cur = 0;
    for (int ck = 0; ck < 32; ++ck) {
        __syncthreads();                       // buf[cur] loaded; buf[cur^1] free
        if (ck + 1 < 32) K1_STAGE(ck + 1, cur ^ 1);
        const char* As = lds + cur * 32768;
        const char* Bs = As + 16384;
#pragma unroll
        for (int ks = 0; ks < 2; ++ks) {
            half8v ah[2], al[2], bh[2], bl[2];
#pragma unroll
            for (int f = 0; f < 2; ++f) {
                ah[f] = *(const half8v*)(As + aoff[f][ks]);
                al[f] = *(const half8v*)(As + (aoff[f][ks] ^ 64));
                bh[f] = *(const half8v*)(Bs + boff[f][ks]);
                bl[f] = *(const half8v*)(Bs + (boff[f][ks] ^ 64));
            }
#pragma unroll
            for (int fm = 0; fm < 2; ++fm)
#pragma unroll
                for (int fn = 0; fn < 2; ++fn) {
                    acc[fm][fn] = __builtin_amdgcn_mfma_f32_32x32x16_f16(ah[fm], bh[fn], acc[fm][fn], 0, 0, 0);
                    acc[fm][fn] = __builtin_amdgcn_mfma_f32_32x32x16_f16(ah[fm], bl[fn], acc[fm][fn], 0, 0, 0);
                    acc[fm][fn] = __builtin_amdgcn_mfma_f32_32x32x16_f16(al[fm], bh[fn], acc[fm][fn], 0, 0, 0);
                }
        }
        cur ^= 1;
    }
#pragma unroll
    for (int fm = 0; fm < 2; ++fm)
#pragma unroll
        for (int fn = 0; fn < 2; ++fn)
#pragma unroll
            for (int g = 0; g < 16; ++g) {
                int rr = (g & 3) + 8 * (g >> 2) + 4 * lhi;
                int row = wrow * 64 + fm * 32 + rr;
                int col = wcol * 64 + fn * 32 + l31;
                Sb[(size_t)row * TT + col] = acc[fm][fn][g];
            }
}

// --- k1b: softmax, row cached in regs, writes P into K2's tiled layout -----
__global__ __launch_bounds__(256) void k1b2(const float* __restrict__ S,
                                            f16* __restrict__ Pt) {
    __shared__ float red[4];
    int rowid = blockIdx.x;
    int b = rowid >> 11, t = rowid & (TT - 1);
    const float* Sr = S + ((size_t)b * TT + t) * TT;
    int tid = threadIdx.x;
    int nv = t + 1;
    int mi = t >> 7, r = t & 127;
    int rowend = (mi + 1) << 7;
    int c = tid * 8;

    float4 x0 = *(const float4*)(Sr + c);
    float4 x1 = *(const float4*)(Sr + c + 4);
    float v[8] = {x0.x, x0.y, x0.z, x0.w, x1.x, x1.y, x1.z, x1.w};

    float m = -3.0e38f;
#pragma unroll
    for (int j = 0; j < 8; ++j)
        if (c + j < nv) m = fmaxf(m, v[j]);
#pragma unroll
    for (int o = 32; o > 0; o >>= 1) m = fmaxf(m, __shfl_xor(m, o));
    if ((tid & 63) == 0) red[tid >> 6] = m;
    __syncthreads();
    m = fmaxf(fmaxf(red[0], red[1]), fmaxf(red[2], red[3]));
    __syncthreads();

    float e[8];
    float s = 0.f;
#pragma unroll
    for (int j = 0; j < 8; ++j) {
        e[j] = (c + j < nv) ? exp2f((v[j] - m) * L2E) : 0.0f;
        s += e[j];
    }
#pragma unroll
    for (int o = 32; o > 0; o >>= 1) s += __shfl_xor(s, o);
    if ((tid & 63) == 0) red[tid >> 6] = s;
    __syncthreads();
    s = red[0] + red[1] + red[2] + red[3];
    float inv = 1.0f / s;

    if (c < rowend) {
        half8v h;
#pragma unroll
        for (int j = 0; j < 8; ++j) h[j] = (f16)(e[j] * inv);
        char* dst = (char*)Pt + ((size_t)((b * 16 + mi) * 32 + (c >> 6))) * 16384
                    + r * 128 + ((((c >> 3) & 7) ^ (r & 7)) << 4);
        *(half8v*)dst = h;
    }
}

// --- K2: O = P V, gload_lds 2-phase, BK=64 ---------------------------------
__global__ __launch_bounds__(256, 2) void k2_pv2(const f16* __restrict__ Pt,
                                                 const f16* __restrict__ Vt,
                                                 float* __restrict__ O) {
    __shared__ char lds[65536];

    int bid0 = blockIdx.x;
    int bid = (bid0 & 7) * (512 / 8) + (bid0 >> 3);    // XCD swizzle (512%8==0)
    int b = bid >> 7, mi = (bid >> 3) & 15, nj = bid & 7;
    int kc = (mi + 1) * 2;                             // chunks of BK=64

    const char* Abase = (const char*)Pt + ((size_t)((b * 16 + mi) * 32)) * 16384;
    const char* Bbase = (const char*)Vt + ((size_t)((b * 8 + nj) * 32)) * 16384;
    float* Ob = O + (size_t)b * TT * DD + (size_t)(mi * 128) * DD + nj * 128;

    int tid = threadIdx.x;
    int lane = tid & 63;
    int wv = tid >> 6;
    int l31 = lane & 31, lhi = lane >> 5;
    int wrow = wv >> 1, wcol = wv & 1;

    int aoff[2][4], boff[2][4];
#pragma unroll
    for (int f = 0; f < 2; ++f) {
        int ra = wrow * 64 + f * 32 + l31;
        int rb = wcol * 64 + f * 32 + l31;
#pragma unroll
        for (int ks = 0; ks < 4; ++ks) {
            int slot = ks * 2 + lhi;
            aoff[f][ks] = ra * 128 + ((slot ^ (ra & 7)) << 4);
            boff[f][ks] = rb * 128 + ((slot ^ (rb & 7)) << 4);
        }
    }
    int lane_go = (wv * 256 + lane) * 16;
    int lane_lo = (wv * 256) * 16;

    f32x16 acc[2][2] = {};

#define K2_STAGE(CK, BUF)                                                       \
    {                                                                           \
        const char* ga = Abase + (size_t)(CK) * 16384 + lane_go;                \
        const char* gb = Bbase + (size_t)(CK) * 16384 + lane_go;                \
        char* la = lds + (BUF) * 32768 + lane_lo;                               \
        char* lb = la + 16384;                                                  \
        _Pragma("unroll") for (int i = 0; i < 4; ++i)                           \
            gload16(ga + i * 1024, la + i * 1024);                              \
        _Pragma("unroll") for (int i = 0; i < 4; ++i)                           \
            gload16(gb + i * 1024, lb + i * 1024);                              \
    }

    K2_STAGE(0, 0);
    int cur = 0;
    for (int ck = 0; ck < kc; ++ck) {
        __syncthreads();
        if (ck + 1 < kc) K2_STAGE(ck + 1, cur ^ 1);
        const char* As = lds + cur * 32768;
        const char* Bs = As + 16384;
#pragma unroll
        for (int ks = 0; ks < 4; ++ks) {
            half8v a0 = *(const half8v*)(As + aoff[0][ks]);
            half8v a1 = *(const half8v*)(As + aoff[1][ks]);
            half8v b0 = *(const half8v*)(Bs + boff[0][ks]);
            half8v b1 = *(const half8v*)(Bs + boff[1][ks]);
            acc[0][0] = __builtin_amdgcn_mfma_f32_32x32x16_f16(a0, b0, acc[0][0], 0, 0, 0);
            acc[0][1] = __builtin_amdgcn_mfma_f32_32x32x16_f16(a0, b1, acc[0][1], 0, 0, 0);
            acc[1][0] = __builtin_amdgcn_mfma_f32_32x32x16_f16(a1, b0, acc[1][0], 0, 0, 0);
            acc[1][1] = __builtin_amdgcn_mfma_f32_32x32x16_f16(a1, b1, acc[1][1], 0, 0, 0);
        }
        cur ^= 1;
    }
#pragma unroll
    for (int fm = 0; fm < 2; ++fm)
#pragma unroll
        for (int fn = 0; fn < 2; ++fn)
#pragma unroll
            for (int g = 0; g < 16; ++g) {
                int rr = (g & 3) + 8 * (g >> 2) + 4 * lhi;
                int row = wrow * 64 + fm * 32 + rr;
                int col = wcol * 64 + fn * 32 + l31;
                Ob[(size_t)row * DD + col] = acc[fm][fn][g];
            }
}

// ===========================================================================
// r1 FALLBACK PATH (ws >= 96 MiB) — unchanged, proven correct
// ===========================================================================
__global__ __launch_bounds__(256, 2) void k1_qk(const float* __restrict__ Q,
                                                const float* __restrict__ Kmat,
                                                float* __restrict__ S) {
    __shared__ f16 Ah[128][36], Al[128][36], Bh[128][36], Bl[128][36];
    int bid = blockIdx.x;
    int b = bid / NTILE, r = bid % NTILE;
    int mi = 0;
    while ((mi + 1) * (mi + 2) / 2 <= r) ++mi;
    int nj = r - mi * (mi + 1) / 2;
    const float* Qb = Q + ((size_t)b * TT + (size_t)mi * 128) * DD;
    const float* Kb = Kmat + ((size_t)b * TT + (size_t)nj * 128) * DD;
    float* Sb = S + (size_t)b * TT * TT + (size_t)(mi * 128) * TT + nj * 128;
    int tid = threadIdx.x;
    int lane = tid & 63;
    int wave = tid >> 6;
    int l31 = lane & 31, lhi = lane >> 5;
    int wrow = wave >> 1, wcol = wave & 1;
    int r0 = tid >> 1;
    int c0 = (tid & 1) * 16;
    f32x16 acc[2][2] = {};
    float4 abuf[4], bbuf[4];
#pragma unroll
    for (int j = 0; j < 4; ++j) {
        abuf[j] = *(const float4*)(Qb + (size_t)r0 * DD + c0 + 4 * j);
        bbuf[j] = *(const float4*)(Kb + (size_t)r0 * DD + c0 + 4 * j);
    }
    for (int ch = 0; ch < DD / 32; ++ch) {
        __syncthreads();
#pragma unroll
        for (int j = 0; j < 4; ++j) {
            float4 a = abuf[j], bq = bbuf[j];
            float ax[4] = {a.x * SCALE, a.y * SCALE, a.z * SCALE, a.w * SCALE};
            float bx[4] = {bq.x, bq.y, bq.z, bq.w};
            half4v ahv, alv, bhv, blv;
#pragma unroll
            for (int e = 0; e < 4; ++e) {
                f16 h = (f16)ax[e];
                ahv[e] = h;
                alv[e] = (f16)(ax[e] - (float)h);
                f16 g = (f16)bx[e];
                bhv[e] = g;
                blv[e] = (f16)(bx[e] - (float)g);
            }
            *(half4v*)&Ah[r0][c0 + 4 * j] = ahv;
            *(half4v*)&Al[r0][c0 + 4 * j] = alv;
            *(half4v*)&Bh[r0][c0 + 4 * j] = bhv;
            *(half4v*)&Bl[r0][c0 + 4 * j] = blv;
        }
        __syncthreads();
        if (ch + 1 < DD / 32) {
            int ck = (ch + 1) * 32;
#pragma unroll
            for (int j = 0; j < 4; ++j) {
                abuf[j] = *(const float4*)(Qb + (size_t)r0 * DD + ck + c0 + 4 * j);
                bbuf[j] = *(const float4*)(Kb + (size_t)r0 * DD + ck + c0 + 4 * j);
            }
        }
#pragma unroll
        for (int ks = 0; ks < 2; ++ks) {
            int kb = ks * 16 + lhi * 8;
            half8v ahf[2], alf[2], bhf[2], blf[2];
#pragma unroll
            for (int f = 0; f < 2; ++f) {
                ahf[f] = ld_frag(&Ah[wrow * 64 + f * 32 + l31][kb]);
                alf[f] = ld_frag(&Al[wrow * 64 + f * 32 + l31][kb]);
                bhf[f] = ld_frag(&Bh[wcol * 64 + f * 32 + l31][kb]);
                blf[f] = ld_frag(&Bl[wcol * 64 + f * 32 + l31][kb]);
            }
#pragma unroll
            for (int fm = 0; fm < 2; ++fm)
#pragma unroll
                for (int fn = 0; fn < 2; ++fn) {
                    acc[fm][fn] = __builtin_amdgcn_mfma_f32_32x32x16_f16(ahf[fm], bhf[fn], acc[fm][fn], 0, 0, 0);
                    acc[fm][fn] = __builtin_amdgcn_mfma_f32_32x32x16_f16(ahf[fm], blf[fn], acc[fm][fn], 0, 0, 0);
                    acc[fm][fn] = __builtin_amdgcn_mfma_f32_32x32x16_f16(alf[fm], bhf[fn], acc[fm][fn], 0, 0, 0);
                }
        }
    }
#pragma unroll
    for (int fm = 0; fm < 2; ++fm)
#pragma unroll
        for (int fn = 0; fn < 2; ++fn)
#pragma unroll
            for (int g = 0; g < 16; ++g) {
                int rr = (g & 3) + 8 * (g >> 2) + 4 * lhi;
                int row = wrow * 64 + fm * 32 + rr;
                int col = wcol * 64 + fn * 32 + l31;
                Sb[(size_t)row * TT + col] = acc[fm][fn][g];
            }
}

__global__ __launch_bounds__(256) void k1b_softmax(const float* __restrict__ S,
                                                   f16* __restrict__ P) {
    __shared__ float red[4];
    int rowid = blockIdx.x;
    int b = rowid >> 11, t = rowid & (TT - 1);
    const float* Sr = S + (size_t)b * TT * TT + (size_t)t * TT;
    f16* Pr = P + (size_t)b * TT * TT + (size_t)t * TT;
    int tid = threadIdx.x;
    int nv = t + 1;
    int rowend = ((t >> 7) + 1) << 7;
    float m = -3.0e38f;
    for (int c = tid; c < nv; c += 256) m = fmaxf(m, Sr[c]);
#pragma unroll
    for (int o = 32; o > 0; o >>= 1) m = fmaxf(m, __shfl_xor(m, o));
    if ((tid & 63) == 0) red[tid >> 6] = m;
    __syncthreads();
    m = fmaxf(fmaxf(red[0], red[1]), fmaxf(red[2], red[3]));
    __syncthreads();
    float s = 0.f;
    for (int c = tid; c < nv; c += 256) s += exp2f((Sr[c] - m) * L2E);
#pragma unroll
    for (int o = 32; o > 0; o >>= 1) s += __shfl_xor(s, o);
    if ((tid & 63) == 0) red[tid >> 6] = s;
    __syncthreads();
    s = red[0] + red[1] + red[2] + red[3];
    float inv = 1.0f / s;
    for (int c = tid; c < rowend; c += 256) {
        float p = (c < nv) ? exp2f((Sr[c] - m) * L2E) * inv : 0.0f;
        Pr[c] = (f16)p;
    }
}

__global__ __launch_bounds__(256, 2) void k2_pv(const f16* __restrict__ P,
                                                const float* __restrict__ V,
                                                float* __restrict__ O) {
    __shared__ f16 Pa[128][36];
    __shared__ f16 Vt[128][36];
    int bid = blockIdx.x;
    int b = bid >> 7;
    int rest = bid & 127;
    int mi = rest >> 3, nj = rest & 7;
    int kend = (mi + 1) * 128;
    const f16* Pb = P + (size_t)b * TT * TT + (size_t)(mi * 128) * TT;
    const float* Vb = V + (size_t)b * TT * DD + nj * 128;
    float* Ob = O + (size_t)b * TT * DD + (size_t)(mi * 128) * DD + nj * 128;
    int tid = threadIdx.x;
    int lane = tid & 63;
    int wave = tid >> 6;
    int l31 = lane & 31, lhi = lane >> 5;
    int wrow = wave >> 1, wcol = wave & 1;
    f32x16 acc[2][2] = {};
    int pr = tid >> 1, pc = (tid & 1) * 16;
    int vk = tid >> 3, vn = (tid & 7) * 16;
    uint2 pbuf[4];
    float4 vbuf[4];
#pragma unroll
    for (int j = 0; j < 4; ++j) {
        pbuf[j] = *(const uint2*)(Pb + (size_t)pr * TT + pc + 4 * j);
        vbuf[j] = *(const float4*)(Vb + (size_t)vk * DD + vn + 4 * j);
    }
    for (int ck = 0; ck < kend; ck += 32) {
        __syncthreads();
#pragma unroll
        for (int j = 0; j < 4; ++j) {
            *(uint2*)&Pa[pr][pc + 4 * j] = pbuf[j];
            float4 v = vbuf[j];
            float vv[4] = {v.x, v.y, v.z, v.w};
            int n0 = vn + 4 * j;
#pragma unroll
            for (int e = 0; e < 4; ++e) {
                int n = n0 + e;
                Vt[n][vk ^ ((((unsigned)n >> 4) & 3) << 3)] = (f16)vv[e];
            }
        }
        __syncthreads();
        if (ck + 32 < kend) {
            int cn = ck + 32;
#pragma unroll
            for (int j = 0; j < 4; ++j) {
                pbuf[j] = *(const uint2*)(Pb + (size_t)pr * TT + cn + pc + 4 * j);
                vbuf[j] = *(const float4*)(Vb + (size_t)(cn + vk) * DD + vn + 4 * j);
            }
        }
#pragma unroll
        for (int ks = 0; ks < 2; ++ks) {
            int kb = ks * 16 + lhi * 8;
            half8v paf[2], vbf[2];
#pragma unroll
            for (int f = 0; f < 2; ++f) {
                paf[f] = ld_frag(&Pa[wrow * 64 + f * 32 + l31][kb]);
                int n = wcol * 64 + f * 32 + l31;
                int kbs = kb ^ ((((unsigned)n >> 4) & 3) << 3);
                vbf[f] = ld_frag(&Vt[n][kbs]);
            }
#pragma unroll
            for (int fm = 0; fm < 2; ++fm)
#pragma unroll
                for (int fn = 0; fn < 2; ++fn)
                    acc[fm][fn] = __builtin_amdgcn_mfma_f32_32x32x16_f16(paf[fm], vbf[fn], acc[fm][fn], 0, 0, 0);
        }
    }
#pragma unroll
    for (int fm = 0; fm < 2; ++fm)
#pragma unroll
        for (int fn = 0; fn < 2; ++fn)
#pragma unroll
            for (int g = 0; g < 16; ++g) {
                int rr = (g & 3) + 8 * (g >> 2) + 4 * lhi;
                int row = wrow * 64 + fm * 32 + rr;
                int col = wcol * 64 + fn * 32 + l31;
                Ob[(size_t)row * DD + col] = acc[fm][fn][g];
            }
}

__global__ __launch_bounds__(256) void fa_fallback(const float* __restrict__ Q,
                                                   const float* __restrict__ Kmat,
                                                   const float* __restrict__ V,
                                                   float* __restrict__ O) {
    __shared__ float qs[DD];
    __shared__ float osum[DD];
    __shared__ float red[4];
    int rowid = blockIdx.x;
    int b = rowid >> 11, t = rowid & (TT - 1);
    const float* q = Q + ((size_t)b * TT + t) * DD;
    int tid = threadIdx.x;
    for (int j = tid; j < DD; j += 256) { qs[j] = q[j] * SCALE; osum[j] = 0.f; }
    __syncthreads();
    float m = -3.0e38f, l = 0.f;
    for (int s = 0; s <= t; ++s) {
        const float* kr = Kmat + ((size_t)b * TT + s) * DD;
        float part = 0.f;
#pragma unroll
        for (int j = 0; j < 4; ++j) part += qs[tid * 4 + j] * kr[tid * 4 + j];
#pragma unroll
        for (int o = 32; o > 0; o >>= 1) part += __shfl_xor(part, o);
        if ((tid & 63) == 0) red[tid >> 6] = part;
        __syncthreads();
        float dot = red[0] + red[1] + red[2] + red[3];
        float mn = fmaxf(m, dot);
        float f = exp2f((m - mn) * 1.44269504f);
        float e = exp2f((dot - mn) * 1.44269504f);
        l = l * f + e;
        const float* vr = V + ((size_t)b * TT + s) * DD;
#pragma unroll
        for (int j = 0; j < 4; ++j) {
            int c = tid * 4 + j;
            osum[c] = osum[c] * f + e * vr[c];
        }
        m = mn;
        __syncthreads();
    }
    float inv = 1.f / l;
    for (int j = tid; j < DD; j += 256) O[((size_t)b * TT + t) * DD + j] = osum[j] * inv;
}

extern "C" void kernel_launch(void* const* d_in, const int* in_sizes, int n_in,
                              void* d_out, int out_size, void* d_ws, size_t ws_size,
                              hipStream_t stream) {
    const float* Q = (const float*)d_in[0];
    const float* K = (const float*)d_in[1];
    const float* V = (const float*)d_in[2];
    float* O = (float*)d_out;

    const size_t MB = 1024 * 1024;
    const size_t QT_B = 32 * MB, KT_B = 32 * MB, VT_B = 16 * MB, S_B = 64 * MB;
    const size_t FULL = QT_B + KT_B + VT_B + S_B;   // 144 MiB (P aliases Qt)

    size_t sbytes = (size_t)BB * TT * TT * 4;
    size_t pbytes = (size_t)BB * TT * TT * 2;

    if (ws_size >= FULL) {
        f16* Qt = (f16*)d_ws;
        f16* Kt = (f16*)((char*)d_ws + QT_B);
        f16* Vt = (f16*)((char*)d_ws + QT_B + KT_B);
        float* S = (float*)((char*)d_ws + QT_B + KT_B + VT_B);
        f16* Pt = (f16*)d_ws;   // aliases Qt (dead after k1)
        hipLaunchKernelGGL(repack_qk, dim3(2048), dim3(256), 0, stream, Q, K, Qt, Kt);
        hipLaunchKernelGGL(transpose_v, dim3(1024), dim3(256), 0, stream, V, Vt);
        hipLaunchKernelGGL(k1_qk2, dim3(BB * NTILE), dim3(256), 0, stream, Qt, Kt, S);
        hipLaunchKernelGGL(k1b2, dim3(BB * TT), dim3(256), 0, stream, S, Pt);
        hipLaunchKernelGGL(k2_pv2, dim3(512), dim3(256), 0, stream, Pt, Vt, O);
    } else if (ws_size >= sbytes + pbytes) {
        float* S = (float*)d_ws;
        f16* P = (f16*)((char*)d_ws + sbytes);
        hipLaunchKernelGGL(k1_qk, dim3(BB * NTILE), dim3(256), 0, stream, Q, K, S);
        hipLaunchKernelGGL(k1b_softmax, dim3(BB * TT), dim3(256), 0, stream, S, P);
        hipLaunchKernelGGL(k2_pv, dim3(BB * 16 * 8), dim3(256), 0, stream, P, V, O);
    } else {
        hipLaunchKernelGGL(fa_fallback, dim3(BB * TT), dim3(256), 0, stream, Q, K, V, O);
    }
}